// Round 6
// baseline (334.381 us; speedup 1.0000x reference)
//
#include <hip/hip_runtime.h>
#include <stdint.h>

typedef unsigned short u16;
typedef unsigned char u8;
typedef __attribute__((ext_vector_type(8))) short short8;
typedef __attribute__((ext_vector_type(4))) float f32x4;
typedef __attribute__((ext_vector_type(16))) float f32x16;
typedef __attribute__((ext_vector_type(4))) int i32x4;
typedef __attribute__((ext_vector_type(8))) int i32x8;

#define BATCH 16384L
#define WSCALE 64.0f
#define INV_WSCALE (1.0f / 64.0f)
#define SCALE_ONE 0x7f7f7f7f   // e8m0 biased exp 127 = 1.0 in all 4 bytes

__device__ __forceinline__ u16 f2bf(float f) {
    union { float f; uint32_t u; } cv; cv.f = f;
    uint32_t u = cv.u;
    u = (u + 0x7fffu + ((u >> 16) & 1u)) >> 16;
    return (u16)u;
}
__device__ __forceinline__ u16 f2bf_trunc(float f) {
    union { float f; uint32_t u; } cv; cv.f = f;
    return (u16)(cv.u >> 16);
}
__device__ __forceinline__ float bf2f(u16 h) {
    union { uint32_t u; float f; } cv; cv.u = ((uint32_t)h) << 16;
    return cv.f;
}
template<bool HI>
__device__ __forceinline__ uint32_t fp8pk(float a, float b, uint32_t old) {
    return (uint32_t)__builtin_amdgcn_cvt_pk_fp8_f32(a, b, (int)old, HI);
}
__device__ __forceinline__ u8 f2fp8(float v) {
    return (u8)(__builtin_amdgcn_cvt_pk_fp8_f32(v, v, 0, false) & 0xff);
}

// ---------------------------------------------------------------------------
// Kernel 1: per-batch gram pairs (truncating hi/lo split bf16 MFMA ~ fp32)
//           + emit fp8 copy of x for GEMM1 (reads x exactly once)
// ---------------------------------------------------------------------------
__global__ __launch_bounds__(256) void k_gram(const float* __restrict__ x,
                                              const float* __restrict__ Wc,
                                              u8* __restrict__ xb,
                                              float* __restrict__ spair) {
    const int wave = threadIdx.x >> 6;
    const int lane = threadIdx.x & 63;
    const long b = (long)blockIdx.x * 4 + wave;
    const int r16 = lane & 15, quad = lane >> 4;
    const float* xg = x + b * 2048;

    short8 hi[2][2], lo[2][2];
    for (int mt = 0; mt < 2; mt++) {
        for (int k0 = 0; k0 < 2; k0++) {
            const int row = mt * 16 + r16;
            const int kof = k0 * 32 + quad * 8;
            const float* p = xg + row * 64 + kof;
            float4 p0 = *(const float4*)p;
            float4 p1 = *(const float4*)(p + 4);
            float v[8] = {p0.x, p0.y, p0.z, p0.w, p1.x, p1.y, p1.z, p1.w};
            short8 h, l;
            for (int j = 0; j < 8; j++) {
                u16 hb = f2bf_trunc(v[j]);          // truncate: lo absorbs the error
                h[j] = (short)hb;
                l[j] = (short)f2bf_trunc(v[j] - bf2f(hb));
            }
            hi[mt][k0] = h; lo[mt][k0] = l;
            uint32_t w0 = fp8pk<false>(v[0], v[1], 0); w0 = fp8pk<true>(v[2], v[3], w0);
            uint32_t w1 = fp8pk<false>(v[4], v[5], 0); w1 = fp8pk<true>(v[6], v[7], w1);
            *(uint2*)(xb + b * 2048 + row * 64 + kof) = make_uint2(w0, w1);
        }
    }
    f32x4 zero = {0.f, 0.f, 0.f, 0.f};
    f32x4 acc[2][2];
    for (int mt = 0; mt < 2; mt++) for (int nt = 0; nt < 2; nt++) acc[mt][nt] = zero;
    for (int k0 = 0; k0 < 2; k0++)
        for (int mt = 0; mt < 2; mt++)
            for (int nt = 0; nt < 2; nt++) {
                acc[mt][nt] = __builtin_amdgcn_mfma_f32_16x16x32_bf16(hi[mt][k0], hi[nt][k0], acc[mt][nt], 0, 0, 0);
                acc[mt][nt] = __builtin_amdgcn_mfma_f32_16x16x32_bf16(hi[mt][k0], lo[nt][k0], acc[mt][nt], 0, 0, 0);
                acc[mt][nt] = __builtin_amdgcn_mfma_f32_16x16x32_bf16(lo[mt][k0], hi[nt][k0], acc[mt][nt], 0, 0, 0);
            }
    float pacc = 0.f;
    for (int mt = 0; mt < 2; mt++)
        for (int nt = 0; nt < 2; nt++)
            for (int r = 0; r < 4; r++) {
                int row = mt * 16 + quad * 4 + r;
                int col = nt * 16 + r16;
                if (col > row) {
                    int p = 31 * row - (row * (row - 1)) / 2 + (col - row - 1);
                    pacc += acc[mt][nt][r] * Wc[64 + p];
                }
            }
    for (int off = 1; off < 64; off <<= 1) pacc += __shfl_xor(pacc, off);
    if (lane == 0) spair[b] = pacc;
}

// ---------------------------------------------------------------------------
// Kernel 2: fp32 -> fp8 transpose, value = WSCALE * (scale[k]?) * W[k,n]
// ---------------------------------------------------------------------------
__global__ __launch_bounds__(256) void k_transpose_fp8(const float* __restrict__ W,
                                                       const float* __restrict__ scale,
                                                       u8* __restrict__ WT,
                                                       int K, int N) {
    __shared__ float tile[32][33];
    const int nb = blockIdx.x * 32, kb = blockIdx.y * 32;
    const int tx = threadIdx.x & 31, ty = threadIdx.x >> 5;  // ty 0..7
    if (scale) {
        for (int r = ty; r < 32; r += 8)
            tile[r][tx] = scale[kb + r] * W[(long)(kb + r) * N + nb + tx];
    } else {
        for (int r = ty; r < 32; r += 8)
            tile[r][tx] = W[(long)(kb + r) * N + nb + tx];
    }
    __syncthreads();
    for (int r = ty; r < 32; r += 8)
        WT[(long)(nb + r) * K + kb + tx] = f2fp8(WSCALE * tile[tx][r]);
}

// ---------------------------------------------------------------------------
// 32B fragment from XOR-swizzled LDS row: two independently-indexed 16B chunks
// ---------------------------------------------------------------------------
__device__ __forceinline__ i32x8 frag32(const u8* __restrict__ lds, int R, int cb) {
    const int s = R & 7;
    i32x4 lo = *(const i32x4*)&lds[R * 128 + ((cb ^ s) * 16)];
    i32x4 hi = *(const i32x4*)&lds[R * 128 + (((cb + 1) ^ s) * 16)];
    i32x8 r;
    r[0] = lo[0]; r[1] = lo[1]; r[2] = lo[2]; r[3] = lo[3];
    r[4] = hi[0]; r[5] = hi[1]; r[6] = hi[2]; r[7] = hi[3];
    return r;
}

// ---------------------------------------------------------------------------
// Kernel 3: MX-scaled fp8 GEMM (32x32x64, scales=1.0), BK=128, DOUBLE-BUFFERED
//           LDS (one barrier/iter, staging of tile i+1 overlaps compute of i),
//           XOR-swizzle, XCD-aware block swizzle. C = relu(inv*acc+bias) -> fp8
//           + per-column sum/sumsq atomics. M=16384 (128 bands).
// ---------------------------------------------------------------------------
template<int LOGNB>
__global__ __launch_bounds__(256) void gemm_bn(const u8* __restrict__ A,
                                               const u8* __restrict__ Bt,
                                               const float* __restrict__ bias,
                                               u8* __restrict__ C,
                                               float* __restrict__ sums,
                                               float* __restrict__ ssq,
                                               int N, int K, float inv) {
    __shared__ u8 lA[2][128 * 128];
    __shared__ u8 lB[2][128 * 128];
    const int tid = threadIdx.x;
    const int lane = tid & 63, wave = tid >> 6;
    const int wm = wave >> 1, wn = wave & 1;
    const int r32 = lane & 31, hf = lane >> 5;
    const int lid = blockIdx.x;
    const int xcd = lid & 7, t = lid >> 3;
    const int nbk = t & ((1 << LOGNB) - 1);
    const int mbk = (xcd << 4) + (t >> LOGNB);   // 16 bands per XCD
    const long m0 = (long)mbk * 128;
    const long n0 = (long)nbk * 128;

    f32x16 acc[2][2];
    for (int mt = 0; mt < 2; mt++)
        for (int nt = 0; nt < 2; nt++)
            for (int r = 0; r < 16; r++) acc[mt][nt][r] = 0.f;

    const int nit = K >> 7;

    auto stage = [&](int buf, long k0) {
        for (int i = 0; i < 4; i++) {
            const int c = tid + 256 * i;            // 0..1023: 128 rows x 8 chunks
            const int row = c >> 3, pos = c & 7;
            const int g = pos ^ (row & 7);          // source global chunk
            const u8* ga = A + (m0 + row) * K + k0 + g * 16;
            const u8* gb = Bt + (n0 + row) * K + k0 + g * 16;
            __builtin_amdgcn_global_load_lds((const __attribute__((address_space(1))) void*)ga,
                                             (__attribute__((address_space(3))) void*)(&lA[buf][c * 16]), 16, 0, 0);
            __builtin_amdgcn_global_load_lds((const __attribute__((address_space(1))) void*)gb,
                                             (__attribute__((address_space(3))) void*)(&lB[buf][c * 16]), 16, 0, 0);
        }
    };

    stage(0, 0);
    for (int it = 0; it < nit; it++) {
        const int cur = it & 1;
        // barrier: (a) drains this wave's staging of tile `it` (implicit vmcnt(0)),
        // (b) guarantees all waves finished reading buf cur^1 in iter it-1.
        __syncthreads();
        if (it + 1 < nit) stage(cur ^ 1, (long)(it + 1) << 7);
        for (int km = 0; km < 2; km++) {
            const int cb = km * 4 + hf * 2;         // first 16B chunk of this lane's 32B
            i32x8 af[2], bfr[2];
            for (int mt = 0; mt < 2; mt++)
                af[mt] = frag32(lA[cur], wm * 64 + mt * 32 + r32, cb);
            for (int nt = 0; nt < 2; nt++)
                bfr[nt] = frag32(lB[cur], wn * 64 + nt * 32 + r32, cb);
            for (int mt = 0; mt < 2; mt++)
                for (int nt = 0; nt < 2; nt++)
                    acc[mt][nt] = __builtin_amdgcn_mfma_scale_f32_32x32x64_f8f6f4(
                        af[mt], bfr[nt], acc[mt][nt], 0, 0,
                        0, SCALE_ONE, 0, SCALE_ONE);
        }
    }

    // epilogue: C/D 32x32 layout: col=lane&31, row=(reg&3)+8*(reg>>2)+4*(lane>>5)
    for (int nt = 0; nt < 2; nt++) {
        const int col = (int)n0 + wn * 64 + nt * 32 + r32;
        const float bcol = bias[col];
        float s = 0.f, sq = 0.f;
        for (int mt = 0; mt < 2; mt++)
            for (int r = 0; r < 16; r++) {
                const long row = m0 + wm * 64 + mt * 32 + 4 * hf + (r & 3) + 8 * (r >> 2);
                float v = acc[mt][nt][r] * inv + bcol;
                v = fmaxf(v, 0.f);
                C[row * N + col] = f2fp8(v);
                s += v; sq += v * v;
            }
        s += __shfl_xor(s, 32);
        sq += __shfl_xor(sq, 32);
        if (hf == 0) { atomicAdd(&sums[col], s); atomicAdd(&ssq[col], sq); }
    }
}

// ---------------------------------------------------------------------------
// Kernel 4: finalize BN affine: a = g*rsqrt(var+eps), c = beta - a*mean
// ---------------------------------------------------------------------------
__global__ void k_stat(const float* __restrict__ sums, const float* __restrict__ ssq,
                       const float* __restrict__ g, const float* __restrict__ beta,
                       float* __restrict__ a, float* __restrict__ c, int n, float invB) {
    const int k = blockIdx.x * 256 + threadIdx.x;
    if (k < n) {
        const float m = sums[k] * invB;
        const float var = ssq[k] * invB - m * m;
        const float s = g[k] * rsqrtf(var + 1e-5f);
        a[k] = s; c[k] = beta[k] - s * m;
    }
}

// ---------------------------------------------------------------------------
// Kernel 4b: stat2 + head-fold in one dispatch.
// ---------------------------------------------------------------------------
__global__ void k_stat2v(const float* __restrict__ sums, const float* __restrict__ ssq,
                         const float* __restrict__ g, const float* __restrict__ beta,
                         float* __restrict__ a, float* __restrict__ c, float invB,
                         const float* __restrict__ W3, const float* __restrict__ b3,
                         const float* __restrict__ Wc, const float* __restrict__ bc,
                         float* __restrict__ v, float* __restrict__ c0) {
    if (blockIdx.x < 2) {
        const int k = blockIdx.x * 256 + threadIdx.x;
        const float m = sums[k] * invB;
        const float var = ssq[k] * invB - m * m;
        const float s = g[k] * rsqrtf(var + 1e-5f);
        a[k] = s; c[k] = beta[k] - s * m;
    } else {
        for (int k = threadIdx.x; k < 512; k += 256) {
            float s = 0.f;
            for (int j = 0; j < 64; j++) s += W3[k * 64 + j] * Wc[j];
            v[k] = s;
        }
        if (threadIdx.x == 0) {
            float s = 0.f;
            for (int j = 0; j < 64; j++) s += b3[j] * Wc[j];
            *c0 = s + bc[0];
        }
    }
}

// ---------------------------------------------------------------------------
// Kernel 5: b2a[n] = b2[n] + sum_k c1[k]*W2[k,n] — coalesced (lane = col)
// ---------------------------------------------------------------------------
__global__ __launch_bounds__(64) void k_b2adj(const float* __restrict__ W2,
                                              const float* __restrict__ c1,
                                              const float* __restrict__ b2,
                                              float* __restrict__ b2a) {
    const int col = blockIdx.x * 64 + threadIdx.x;   // 8 blocks x 64 lanes
    float s = 0.f;
    for (int k = 0; k < 1024; k++) s += c1[k] * W2[(long)k * 512 + col];
    b2a[col] = b2[col] + s;
}

// ---------------------------------------------------------------------------
// Kernel 7: out[b] = sum_k (a2[k]*h2[b,k]+c2[k])*v[k] + spair[b] + c0
// ---------------------------------------------------------------------------
__global__ __launch_bounds__(256) void k_final(const u8* __restrict__ h2,
                                               const float* __restrict__ a2,
                                               const float* __restrict__ c2,
                                               const float* __restrict__ v,
                                               const float* __restrict__ c0,
                                               const float* __restrict__ spair,
                                               float* __restrict__ out) {
    const int wave = threadIdx.x >> 6, lane = threadIdx.x & 63;
    const long b = (long)blockIdx.x * 4 + wave;
    const int k0 = lane * 8;
    uint2 hv = *(const uint2*)&h2[b * 512 + k0];
    float f[8];
    f[0] = __builtin_amdgcn_cvt_f32_fp8(hv.x, 0);
    f[1] = __builtin_amdgcn_cvt_f32_fp8(hv.x, 1);
    f[2] = __builtin_amdgcn_cvt_f32_fp8(hv.x, 2);
    f[3] = __builtin_amdgcn_cvt_f32_fp8(hv.x, 3);
    f[4] = __builtin_amdgcn_cvt_f32_fp8(hv.y, 0);
    f[5] = __builtin_amdgcn_cvt_f32_fp8(hv.y, 1);
    f[6] = __builtin_amdgcn_cvt_f32_fp8(hv.y, 2);
    f[7] = __builtin_amdgcn_cvt_f32_fp8(hv.y, 3);
    float acc = 0.f;
    for (int j = 0; j < 8; j++) {
        const int k = k0 + j;
        acc += (a2[k] * f[j] + c2[k]) * v[k];
    }
    for (int off = 1; off < 64; off <<= 1) acc += __shfl_xor(acc, off);
    if (lane == 0) out[b] = acc + spair[b] + c0[0];
}

// ---------------------------------------------------------------------------
extern "C" void kernel_launch(void* const* d_in, const int* in_sizes, int n_in,
                              void* d_out, int out_size, void* d_ws, size_t ws_size,
                              hipStream_t stream) {
    const float* x     = (const float*)d_in[0];
    const float* W1    = (const float*)d_in[1];
    const float* b1    = (const float*)d_in[2];
    const float* g1    = (const float*)d_in[3];
    const float* beta1 = (const float*)d_in[4];
    const float* W2    = (const float*)d_in[5];
    const float* b2    = (const float*)d_in[6];
    const float* g2    = (const float*)d_in[7];
    const float* beta2 = (const float*)d_in[8];
    const float* W3    = (const float*)d_in[9];
    const float* b3    = (const float*)d_in[10];
    const float* Wc    = (const float*)d_in[11];
    const float* bc    = (const float*)d_in[12];
    float* out = (float*)d_out;

    char* ws = (char*)d_ws;
    size_t o = 0;
    u8* xb  = (u8*)(ws + o); o += BATCH * 2048;             // 33.6 MB fp8
    u8* w1f = (u8*)(ws + o); o += 2048L * 1024;             //  2.1 MB
    u8* w2f = (u8*)(ws + o); o += 1024L * 512;              //  0.5 MB
    u8* h1b = (u8*)(ws + o); o += BATCH * 1024;             // 16.8 MB (raw relu1, fp8)
    u8* h2b = (u8*)(ws + o); o += BATCH * 512;              //  8.4 MB (raw relu2, fp8)
    float* spair = (float*)(ws + o); o += BATCH * 4;
    float* stats = (float*)(ws + o); o += 3072 * 4;
    float* sums1 = stats, *ssq1 = stats + 1024, *sums2 = stats + 2048, *ssq2 = stats + 2560;
    float* a1 = (float*)(ws + o); o += 1024 * 4;
    float* c1 = (float*)(ws + o); o += 1024 * 4;
    float* a2 = (float*)(ws + o); o += 512 * 4;
    float* c2 = (float*)(ws + o); o += 512 * 4;
    float* vv = (float*)(ws + o); o += 512 * 4;
    float* c0 = (float*)(ws + o); o += 4;
    float* b2a = (float*)(ws + o); o += 512 * 4;

    (void)hipMemsetAsync(stats, 0, 3072 * 4, stream);
    k_gram<<<4096, 256, 0, stream>>>(x, Wc, xb, spair);
    k_transpose_fp8<<<dim3(1024 / 32, 2048 / 32), 256, 0, stream>>>(W1, nullptr, w1f, 2048, 1024);
    gemm_bn<3><<<1024, 256, 0, stream>>>(xb, w1f, b1, h1b, sums1, ssq1, 1024, 2048, INV_WSCALE);
    k_stat<<<4, 256, 0, stream>>>(sums1, ssq1, g1, beta1, a1, c1, 1024, 1.f / 16384.f);
    k_transpose_fp8<<<dim3(512 / 32, 1024 / 32), 256, 0, stream>>>(W2, a1, w2f, 1024, 512);
    k_b2adj<<<8, 64, 0, stream>>>(W2, c1, b2, b2a);
    gemm_bn<2><<<512, 256, 0, stream>>>(h1b, w2f, b2a, h2b, sums2, ssq2, 512, 1024, INV_WSCALE);
    k_stat2v<<<3, 256, 0, stream>>>(sums2, ssq2, g2, beta2, a2, c2, 1.f / 16384.f,
                                    W3, b3, Wc, bc, vv, c0);
    k_final<<<4096, 256, 0, stream>>>(h2b, a2, c2, vv, c0, spair, out);
}

// Round 7
// 333.899 us; speedup vs baseline: 1.0014x; 1.0014x over previous
//
#include <hip/hip_runtime.h>
#include <stdint.h>

typedef unsigned short u16;
typedef unsigned char u8;
typedef __attribute__((ext_vector_type(8))) short short8;
typedef __attribute__((ext_vector_type(4))) float f32x4;
typedef __attribute__((ext_vector_type(16))) float f32x16;
typedef __attribute__((ext_vector_type(4))) int i32x4;
typedef __attribute__((ext_vector_type(8))) int i32x8;

#define BATCH 16384L
#define WSCALE 64.0f
#define INV_WSCALE (1.0f / 64.0f)
#define SCALE_ONE 0x7f7f7f7f   // e8m0 biased exp 127 = 1.0 in all 4 bytes

__device__ __forceinline__ u16 f2bf_trunc(float f) {
    union { float f; uint32_t u; } cv; cv.f = f;
    return (u16)(cv.u >> 16);
}
__device__ __forceinline__ float bf2f(u16 h) {
    union { uint32_t u; float f; } cv; cv.u = ((uint32_t)h) << 16;
    return cv.f;
}
template<bool HI>
__device__ __forceinline__ uint32_t fp8pk(float a, float b, uint32_t old) {
    return (uint32_t)__builtin_amdgcn_cvt_pk_fp8_f32(a, b, (int)old, HI);
}
__device__ __forceinline__ u8 f2fp8(float v) {
    return (u8)(__builtin_amdgcn_cvt_pk_fp8_f32(v, v, 0, false) & 0xff);
}

// ---------------------------------------------------------------------------
// Kernel 1: per-batch gram pairs (truncating hi/lo split bf16 MFMA ~ fp32)
//           + emit fp8 copy of x for GEMM1 (reads x exactly once)
// ---------------------------------------------------------------------------
__global__ __launch_bounds__(256) void k_gram(const float* __restrict__ x,
                                              const float* __restrict__ Wc,
                                              u8* __restrict__ xb,
                                              float* __restrict__ spair) {
    const int wave = threadIdx.x >> 6;
    const int lane = threadIdx.x & 63;
    const long b = (long)blockIdx.x * 4 + wave;
    const int r16 = lane & 15, quad = lane >> 4;
    const float* xg = x + b * 2048;

    short8 hi[2][2], lo[2][2];
    for (int mt = 0; mt < 2; mt++) {
        for (int k0 = 0; k0 < 2; k0++) {
            const int row = mt * 16 + r16;
            const int kof = k0 * 32 + quad * 8;
            const float* p = xg + row * 64 + kof;
            float4 p0 = *(const float4*)p;
            float4 p1 = *(const float4*)(p + 4);
            float v[8] = {p0.x, p0.y, p0.z, p0.w, p1.x, p1.y, p1.z, p1.w};
            short8 h, l;
            for (int j = 0; j < 8; j++) {
                u16 hb = f2bf_trunc(v[j]);          // truncate: lo absorbs the error
                h[j] = (short)hb;
                l[j] = (short)f2bf_trunc(v[j] - bf2f(hb));
            }
            hi[mt][k0] = h; lo[mt][k0] = l;
            uint32_t w0 = fp8pk<false>(v[0], v[1], 0); w0 = fp8pk<true>(v[2], v[3], w0);
            uint32_t w1 = fp8pk<false>(v[4], v[5], 0); w1 = fp8pk<true>(v[6], v[7], w1);
            *(uint2*)(xb + b * 2048 + row * 64 + kof) = make_uint2(w0, w1);
        }
    }
    f32x4 zero = {0.f, 0.f, 0.f, 0.f};
    f32x4 acc[2][2];
    for (int mt = 0; mt < 2; mt++) for (int nt = 0; nt < 2; nt++) acc[mt][nt] = zero;
    for (int k0 = 0; k0 < 2; k0++)
        for (int mt = 0; mt < 2; mt++)
            for (int nt = 0; nt < 2; nt++) {
                acc[mt][nt] = __builtin_amdgcn_mfma_f32_16x16x32_bf16(hi[mt][k0], hi[nt][k0], acc[mt][nt], 0, 0, 0);
                acc[mt][nt] = __builtin_amdgcn_mfma_f32_16x16x32_bf16(hi[mt][k0], lo[nt][k0], acc[mt][nt], 0, 0, 0);
                acc[mt][nt] = __builtin_amdgcn_mfma_f32_16x16x32_bf16(lo[mt][k0], hi[nt][k0], acc[mt][nt], 0, 0, 0);
            }
    float pacc = 0.f;
    for (int mt = 0; mt < 2; mt++)
        for (int nt = 0; nt < 2; nt++)
            for (int r = 0; r < 4; r++) {
                int row = mt * 16 + quad * 4 + r;
                int col = nt * 16 + r16;
                if (col > row) {
                    int p = 31 * row - (row * (row - 1)) / 2 + (col - row - 1);
                    pacc += acc[mt][nt][r] * Wc[64 + p];
                }
            }
    for (int off = 1; off < 64; off <<= 1) pacc += __shfl_xor(pacc, off);
    if (lane == 0) spair[b] = pacc;
}

// ---------------------------------------------------------------------------
// Kernel 2: fp32 -> fp8 transpose, value = WSCALE * (scale[k]?) * W[k,n]
// ---------------------------------------------------------------------------
__global__ __launch_bounds__(256) void k_transpose_fp8(const float* __restrict__ W,
                                                       const float* __restrict__ scale,
                                                       u8* __restrict__ WT,
                                                       int K, int N) {
    __shared__ float tile[32][33];
    const int nb = blockIdx.x * 32, kb = blockIdx.y * 32;
    const int tx = threadIdx.x & 31, ty = threadIdx.x >> 5;  // ty 0..7
    if (scale) {
        for (int r = ty; r < 32; r += 8)
            tile[r][tx] = scale[kb + r] * W[(long)(kb + r) * N + nb + tx];
    } else {
        for (int r = ty; r < 32; r += 8)
            tile[r][tx] = W[(long)(kb + r) * N + nb + tx];
    }
    __syncthreads();
    for (int r = ty; r < 32; r += 8)
        WT[(long)(nb + r) * K + kb + tx] = f2fp8(WSCALE * tile[tx][r]);
}

// ---------------------------------------------------------------------------
// 32B fragment from XOR-swizzled LDS row: two independently-indexed 16B chunks
// ---------------------------------------------------------------------------
__device__ __forceinline__ i32x8 frag32(const u8* __restrict__ lds, int R, int cb) {
    const int s = R & 7;
    i32x4 lo = *(const i32x4*)&lds[R * 128 + ((cb ^ s) * 16)];
    i32x4 hi = *(const i32x4*)&lds[R * 128 + (((cb + 1) ^ s) * 16)];
    i32x8 r;
    r[0] = lo[0]; r[1] = lo[1]; r[2] = lo[2]; r[3] = lo[3];
    r[4] = hi[0]; r[5] = hi[1]; r[6] = hi[2]; r[7] = hi[3];
    return r;
}

// ---------------------------------------------------------------------------
// Kernel 3: MX-scaled fp8 GEMM (32x32x64, scales=1.0), BK=128, single 32 KB
//           LDS (occupancy preserved) + REGISTER PREFETCH of tile i+1 (global
//           loads issued before compute of tile i; vmcnt lands at next iter's
//           ds_write). XOR-swizzle, XCD-aware block swizzle.
//           C = relu(inv*acc+bias) -> fp8 + per-column sum/sumsq atomics.
// ---------------------------------------------------------------------------
template<int LOGNB>
__global__ __launch_bounds__(256) void gemm_bn(const u8* __restrict__ A,
                                               const u8* __restrict__ Bt,
                                               const float* __restrict__ bias,
                                               u8* __restrict__ C,
                                               float* __restrict__ sums,
                                               float* __restrict__ ssq,
                                               int N, int K, float inv) {
    __shared__ u8 lA[128 * 128];
    __shared__ u8 lB[128 * 128];
    const int tid = threadIdx.x;
    const int lane = tid & 63, wave = tid >> 6;
    const int wm = wave >> 1, wn = wave & 1;
    const int r32 = lane & 31, hf = lane >> 5;
    const int lid = blockIdx.x;
    const int xcd = lid & 7, t = lid >> 3;
    const int nbk = t & ((1 << LOGNB) - 1);
    const int mbk = (xcd << 4) + (t >> LOGNB);   // 16 bands per XCD
    const long m0 = (long)mbk * 128;
    const long n0 = (long)nbk * 128;

    f32x16 acc[2][2];
    for (int mt = 0; mt < 2; mt++)
        for (int nt = 0; nt < 2; nt++)
            for (int r = 0; r < 16; r++) acc[mt][nt][r] = 0.f;

    const int nit = K >> 7;

    // per-thread staging addresses (4 chunks of A, 4 of B per tile)
    const u8* gaddrA[4];
    const u8* gaddrB[4];
    for (int i = 0; i < 4; i++) {
        const int c = tid + 256 * i;            // 0..1023: 128 rows x 8 chunks
        const int row = c >> 3, pos = c & 7;
        const int g = pos ^ (row & 7);          // source global chunk for this LDS pos
        gaddrA[i] = A + (m0 + row) * K + g * 16;
        gaddrB[i] = Bt + (n0 + row) * K + g * 16;
    }

    i32x4 pa[4], pb[4];
    for (int i = 0; i < 4; i++) {               // preload tile 0
        pa[i] = *(const i32x4*)(gaddrA[i]);
        pb[i] = *(const i32x4*)(gaddrB[i]);
    }

    for (int it = 0; it < nit; it++) {
        __syncthreads();                        // all waves done reading prev tile
        for (int i = 0; i < 4; i++) {           // commit prefetch regs -> LDS
            const int c = tid + 256 * i;
            *(i32x4*)&lA[c * 16] = pa[i];
            *(i32x4*)&lB[c * 16] = pb[i];
        }
        __syncthreads();                        // LDS writes visible
        if (it + 1 < nit) {                     // issue prefetch of next tile;
            const long ko = (long)(it + 1) << 7;  // latency hidden behind compute
            for (int i = 0; i < 4; i++) {
                pa[i] = *(const i32x4*)(gaddrA[i] + ko);
                pb[i] = *(const i32x4*)(gaddrB[i] + ko);
            }
        }
        for (int km = 0; km < 2; km++) {
            const int cb = km * 4 + hf * 2;     // first 16B chunk of this lane's 32B
            i32x8 af[2], bfr[2];
            for (int mt = 0; mt < 2; mt++)
                af[mt] = frag32(lA, wm * 64 + mt * 32 + r32, cb);
            for (int nt = 0; nt < 2; nt++)
                bfr[nt] = frag32(lB, wn * 64 + nt * 32 + r32, cb);
            for (int mt = 0; mt < 2; mt++)
                for (int nt = 0; nt < 2; nt++)
                    acc[mt][nt] = __builtin_amdgcn_mfma_scale_f32_32x32x64_f8f6f4(
                        af[mt], bfr[nt], acc[mt][nt], 0, 0,
                        0, SCALE_ONE, 0, SCALE_ONE);
        }
    }

    // epilogue: C/D 32x32 layout: col=lane&31, row=(reg&3)+8*(reg>>2)+4*(lane>>5)
    for (int nt = 0; nt < 2; nt++) {
        const int col = (int)n0 + wn * 64 + nt * 32 + r32;
        const float bcol = bias[col];
        float s = 0.f, sq = 0.f;
        for (int mt = 0; mt < 2; mt++)
            for (int r = 0; r < 16; r++) {
                const long row = m0 + wm * 64 + mt * 32 + 4 * hf + (r & 3) + 8 * (r >> 2);
                float v = acc[mt][nt][r] * inv + bcol;
                v = fmaxf(v, 0.f);
                C[row * N + col] = f2fp8(v);
                s += v; sq += v * v;
            }
        s += __shfl_xor(s, 32);
        sq += __shfl_xor(sq, 32);
        if (hf == 0) { atomicAdd(&sums[col], s); atomicAdd(&ssq[col], sq); }
    }
}

// ---------------------------------------------------------------------------
// Kernel 4: finalize BN affine: a = g*rsqrt(var+eps), c = beta - a*mean
// ---------------------------------------------------------------------------
__global__ void k_stat(const float* __restrict__ sums, const float* __restrict__ ssq,
                       const float* __restrict__ g, const float* __restrict__ beta,
                       float* __restrict__ a, float* __restrict__ c, int n, float invB) {
    const int k = blockIdx.x * 256 + threadIdx.x;
    if (k < n) {
        const float m = sums[k] * invB;
        const float var = ssq[k] * invB - m * m;
        const float s = g[k] * rsqrtf(var + 1e-5f);
        a[k] = s; c[k] = beta[k] - s * m;
    }
}

// ---------------------------------------------------------------------------
// Kernel 4b: stat2 + head-fold in one dispatch.
// ---------------------------------------------------------------------------
__global__ void k_stat2v(const float* __restrict__ sums, const float* __restrict__ ssq,
                         const float* __restrict__ g, const float* __restrict__ beta,
                         float* __restrict__ a, float* __restrict__ c, float invB,
                         const float* __restrict__ W3, const float* __restrict__ b3,
                         const float* __restrict__ Wc, const float* __restrict__ bc,
                         float* __restrict__ v, float* __restrict__ c0) {
    if (blockIdx.x < 2) {
        const int k = blockIdx.x * 256 + threadIdx.x;
        const float m = sums[k] * invB;
        const float var = ssq[k] * invB - m * m;
        const float s = g[k] * rsqrtf(var + 1e-5f);
        a[k] = s; c[k] = beta[k] - s * m;
    } else {
        for (int k = threadIdx.x; k < 512; k += 256) {
            float s = 0.f;
            for (int j = 0; j < 64; j++) s += W3[k * 64 + j] * Wc[j];
            v[k] = s;
        }
        if (threadIdx.x == 0) {
            float s = 0.f;
            for (int j = 0; j < 64; j++) s += b3[j] * Wc[j];
            *c0 = s + bc[0];
        }
    }
}

// ---------------------------------------------------------------------------
// Kernel 5: b2a[n] = b2[n] + sum_k c1[k]*W2[k,n] — coalesced (lane = col)
// ---------------------------------------------------------------------------
__global__ __launch_bounds__(64) void k_b2adj(const float* __restrict__ W2,
                                              const float* __restrict__ c1,
                                              const float* __restrict__ b2,
                                              float* __restrict__ b2a) {
    const int col = blockIdx.x * 64 + threadIdx.x;   // 8 blocks x 64 lanes
    float s = 0.f;
    for (int k = 0; k < 1024; k++) s += c1[k] * W2[(long)k * 512 + col];
    b2a[col] = b2[col] + s;
}

// ---------------------------------------------------------------------------
// Kernel 7: out[b] = sum_k (a2[k]*h2[b,k]+c2[k])*v[k] + spair[b] + c0
// ---------------------------------------------------------------------------
__global__ __launch_bounds__(256) void k_final(const u8* __restrict__ h2,
                                               const float* __restrict__ a2,
                                               const float* __restrict__ c2,
                                               const float* __restrict__ v,
                                               const float* __restrict__ c0,
                                               const float* __restrict__ spair,
                                               float* __restrict__ out) {
    const int wave = threadIdx.x >> 6, lane = threadIdx.x & 63;
    const long b = (long)blockIdx.x * 4 + wave;
    const int k0 = lane * 8;
    uint2 hv = *(const uint2*)&h2[b * 512 + k0];
    float f[8];
    f[0] = __builtin_amdgcn_cvt_f32_fp8(hv.x, 0);
    f[1] = __builtin_amdgcn_cvt_f32_fp8(hv.x, 1);
    f[2] = __builtin_amdgcn_cvt_f32_fp8(hv.x, 2);
    f[3] = __builtin_amdgcn_cvt_f32_fp8(hv.x, 3);
    f[4] = __builtin_amdgcn_cvt_f32_fp8(hv.y, 0);
    f[5] = __builtin_amdgcn_cvt_f32_fp8(hv.y, 1);
    f[6] = __builtin_amdgcn_cvt_f32_fp8(hv.y, 2);
    f[7] = __builtin_amdgcn_cvt_f32_fp8(hv.y, 3);
    float acc = 0.f;
    for (int j = 0; j < 8; j++) {
        const int k = k0 + j;
        acc += (a2[k] * f[j] + c2[k]) * v[k];
    }
    for (int off = 1; off < 64; off <<= 1) acc += __shfl_xor(acc, off);
    if (lane == 0) out[b] = acc + spair[b] + c0[0];
}

// ---------------------------------------------------------------------------
extern "C" void kernel_launch(void* const* d_in, const int* in_sizes, int n_in,
                              void* d_out, int out_size, void* d_ws, size_t ws_size,
                              hipStream_t stream) {
    const float* x     = (const float*)d_in[0];
    const float* W1    = (const float*)d_in[1];
    const float* b1    = (const float*)d_in[2];
    const float* g1    = (const float*)d_in[3];
    const float* beta1 = (const float*)d_in[4];
    const float* W2    = (const float*)d_in[5];
    const float* b2    = (const float*)d_in[6];
    const float* g2    = (const float*)d_in[7];
    const float* beta2 = (const float*)d_in[8];
    const float* W3    = (const float*)d_in[9];
    const float* b3    = (const float*)d_in[10];
    const float* Wc    = (const float*)d_in[11];
    const float* bc    = (const float*)d_in[12];
    float* out = (float*)d_out;

    char* ws = (char*)d_ws;
    size_t o = 0;
    u8* xb  = (u8*)(ws + o); o += BATCH * 2048;             // 33.6 MB fp8
    u8* w1f = (u8*)(ws + o); o += 2048L * 1024;             //  2.1 MB
    u8* w2f = (u8*)(ws + o); o += 1024L * 512;              //  0.5 MB
    u8* h1b = (u8*)(ws + o); o += BATCH * 1024;             // 16.8 MB (raw relu1, fp8)
    u8* h2b = (u8*)(ws + o); o += BATCH * 512;              //  8.4 MB (raw relu2, fp8)
    float* spair = (float*)(ws + o); o += BATCH * 4;
    float* stats = (float*)(ws + o); o += 3072 * 4;
    float* sums1 = stats, *ssq1 = stats + 1024, *sums2 = stats + 2048, *ssq2 = stats + 2560;
    float* a1 = (float*)(ws + o); o += 1024 * 4;
    float* c1 = (float*)(ws + o); o += 1024 * 4;
    float* a2 = (float*)(ws + o); o += 512 * 4;
    float* c2 = (float*)(ws + o); o += 512 * 4;
    float* vv = (float*)(ws + o); o += 512 * 4;
    float* c0 = (float*)(ws + o); o += 4;
    float* b2a = (float*)(ws + o); o += 512 * 4;

    (void)hipMemsetAsync(stats, 0, 3072 * 4, stream);
    k_gram<<<4096, 256, 0, stream>>>(x, Wc, xb, spair);
    k_transpose_fp8<<<dim3(1024 / 32, 2048 / 32), 256, 0, stream>>>(W1, nullptr, w1f, 2048, 1024);
    gemm_bn<3><<<1024, 256, 0, stream>>>(xb, w1f, b1, h1b, sums1, ssq1, 1024, 2048, INV_WSCALE);
    k_stat<<<4, 256, 0, stream>>>(sums1, ssq1, g1, beta1, a1, c1, 1024, 1.f / 16384.f);
    k_transpose_fp8<<<dim3(512 / 32, 1024 / 32), 256, 0, stream>>>(W2, a1, w2f, 1024, 512);
    k_b2adj<<<8, 64, 0, stream>>>(W2, c1, b2, b2a);
    gemm_bn<2><<<512, 256, 0, stream>>>(h1b, w2f, b2a, h2b, sums2, ssq2, 512, 1024, INV_WSCALE);
    k_stat2v<<<3, 256, 0, stream>>>(sums2, ssq2, g2, beta2, a2, c2, 1.f / 16384.f,
                                    W3, b3, Wc, bc, vv, c0);
    k_final<<<4096, 256, 0, stream>>>(h2b, a2, c2, vv, c0, spair, out);
}

// Round 8
// 312.904 us; speedup vs baseline: 1.0686x; 1.0671x over previous
//
#include <hip/hip_runtime.h>
#include <stdint.h>

typedef unsigned short u16;
typedef unsigned char u8;
typedef __attribute__((ext_vector_type(8))) short short8;
typedef __attribute__((ext_vector_type(4))) float f32x4;
typedef __attribute__((ext_vector_type(16))) float f32x16;
typedef __attribute__((ext_vector_type(4))) int i32x4;
typedef __attribute__((ext_vector_type(8))) int i32x8;

#define BATCH 16384L
#define WSCALE 64.0f
#define INV_WSCALE (1.0f / 64.0f)
#define SCALE_ONE 0x7f7f7f7f   // e8m0 biased exp 127 = 1.0 in all 4 bytes
#define INVB (1.0f / 16384.0f)

__device__ __forceinline__ u16 f2bf_trunc(float f) {
    union { float f; uint32_t u; } cv; cv.f = f;
    return (u16)(cv.u >> 16);
}
__device__ __forceinline__ float bf2f(u16 h) {
    union { uint32_t u; float f; } cv; cv.u = ((uint32_t)h) << 16;
    return cv.f;
}
template<bool HI>
__device__ __forceinline__ uint32_t fp8pk(float a, float b, uint32_t old) {
    return (uint32_t)__builtin_amdgcn_cvt_pk_fp8_f32(a, b, (int)old, HI);
}
__device__ __forceinline__ u8 f2fp8(float v) {
    return (u8)(__builtin_amdgcn_cvt_pk_fp8_f32(v, v, 0, false) & 0xff);
}

// ---------------------------------------------------------------------------
// Kernel 1: per-batch gram pairs (truncating hi/lo split bf16 MFMA ~ fp32)
//           + emit fp8 copy of x for GEMM1 (reads x exactly once)
//           + block 0 zeroes the BN-stats accumulators (replaces memset)
// ---------------------------------------------------------------------------
__global__ __launch_bounds__(256) void k_gram(const float* __restrict__ x,
                                              const float* __restrict__ Wc,
                                              u8* __restrict__ xb,
                                              float* __restrict__ spair,
                                              float* __restrict__ stats) {
    if (blockIdx.x == 0) {
        for (int j = threadIdx.x; j < 3072; j += 256) stats[j] = 0.f;
    }
    const int wave = threadIdx.x >> 6;
    const int lane = threadIdx.x & 63;
    const long b = (long)blockIdx.x * 4 + wave;
    const int r16 = lane & 15, quad = lane >> 4;
    const float* xg = x + b * 2048;

    short8 hi[2][2], lo[2][2];
    for (int mt = 0; mt < 2; mt++) {
        for (int k0 = 0; k0 < 2; k0++) {
            const int row = mt * 16 + r16;
            const int kof = k0 * 32 + quad * 8;
            const float* p = xg + row * 64 + kof;
            float4 p0 = *(const float4*)p;
            float4 p1 = *(const float4*)(p + 4);
            float v[8] = {p0.x, p0.y, p0.z, p0.w, p1.x, p1.y, p1.z, p1.w};
            short8 h, l;
            for (int j = 0; j < 8; j++) {
                u16 hb = f2bf_trunc(v[j]);          // truncate: lo absorbs the error
                h[j] = (short)hb;
                l[j] = (short)f2bf_trunc(v[j] - bf2f(hb));
            }
            hi[mt][k0] = h; lo[mt][k0] = l;
            uint32_t w0 = fp8pk<false>(v[0], v[1], 0); w0 = fp8pk<true>(v[2], v[3], w0);
            uint32_t w1 = fp8pk<false>(v[4], v[5], 0); w1 = fp8pk<true>(v[6], v[7], w1);
            *(uint2*)(xb + b * 2048 + row * 64 + kof) = make_uint2(w0, w1);
        }
    }
    f32x4 zero = {0.f, 0.f, 0.f, 0.f};
    f32x4 acc[2][2];
    for (int mt = 0; mt < 2; mt++) for (int nt = 0; nt < 2; nt++) acc[mt][nt] = zero;
    for (int k0 = 0; k0 < 2; k0++)
        for (int mt = 0; mt < 2; mt++)
            for (int nt = 0; nt < 2; nt++) {
                acc[mt][nt] = __builtin_amdgcn_mfma_f32_16x16x32_bf16(hi[mt][k0], hi[nt][k0], acc[mt][nt], 0, 0, 0);
                acc[mt][nt] = __builtin_amdgcn_mfma_f32_16x16x32_bf16(hi[mt][k0], lo[nt][k0], acc[mt][nt], 0, 0, 0);
                acc[mt][nt] = __builtin_amdgcn_mfma_f32_16x16x32_bf16(lo[mt][k0], hi[nt][k0], acc[mt][nt], 0, 0, 0);
            }
    float pacc = 0.f;
    for (int mt = 0; mt < 2; mt++)
        for (int nt = 0; nt < 2; nt++)
            for (int r = 0; r < 4; r++) {
                int row = mt * 16 + quad * 4 + r;
                int col = nt * 16 + r16;
                if (col > row) {
                    int p = 31 * row - (row * (row - 1)) / 2 + (col - row - 1);
                    pacc += acc[mt][nt][r] * Wc[64 + p];
                }
            }
    for (int off = 1; off < 64; off <<= 1) pacc += __shfl_xor(pacc, off);
    if (lane == 0) spair[b] = pacc;
}

// ---------------------------------------------------------------------------
// Kernel 2: fp32 -> fp8 transpose (W1 path, no scale)
// ---------------------------------------------------------------------------
__global__ __launch_bounds__(256) void k_transpose_fp8(const float* __restrict__ W,
                                                       u8* __restrict__ WT,
                                                       int K, int N) {
    __shared__ float tile[32][33];
    const int nb = blockIdx.x * 32, kb = blockIdx.y * 32;
    const int tx = threadIdx.x & 31, ty = threadIdx.x >> 5;  // ty 0..7
    for (int r = ty; r < 32; r += 8)
        tile[r][tx] = W[(long)(kb + r) * N + nb + tx];
    __syncthreads();
    for (int r = ty; r < 32; r += 8)
        WT[(long)(nb + r) * K + kb + tx] = f2fp8(WSCALE * tile[tx][r]);
}

// ---------------------------------------------------------------------------
// 32B fragment from XOR-swizzled LDS row: two independently-indexed 16B chunks
// ---------------------------------------------------------------------------
__device__ __forceinline__ i32x8 frag32(const u8* __restrict__ lds, int R, int cb) {
    const int s = R & 7;
    i32x4 lo = *(const i32x4*)&lds[R * 128 + ((cb ^ s) * 16)];
    i32x4 hi = *(const i32x4*)&lds[R * 128 + (((cb + 1) ^ s) * 16)];
    i32x8 r;
    r[0] = lo[0]; r[1] = lo[1]; r[2] = lo[2]; r[3] = lo[3];
    r[4] = hi[0]; r[5] = hi[1]; r[6] = hi[2]; r[7] = hi[3];
    return r;
}

// ---------------------------------------------------------------------------
// Kernel 3: MX-scaled fp8 GEMM (32x32x64, scales=1.0), BK=128, single 32 KB
//           LDS buffer + global_load_lds staging (round-5 proven structure).
//           XOR-swizzle, XCD-aware block swizzle. C = relu(inv*acc+bias) ->
//           fp8 + per-column sum/sumsq atomics. M=16384 (128 bands).
// ---------------------------------------------------------------------------
template<int LOGNB>
__global__ __launch_bounds__(256) void gemm_bn(const u8* __restrict__ A,
                                               const u8* __restrict__ Bt,
                                               const float* __restrict__ bias,
                                               u8* __restrict__ C,
                                               float* __restrict__ sums,
                                               float* __restrict__ ssq,
                                               int N, int K, float inv) {
    __shared__ u8 lA[128 * 128];
    __shared__ u8 lB[128 * 128];
    const int tid = threadIdx.x;
    const int lane = tid & 63, wave = tid >> 6;
    const int wm = wave >> 1, wn = wave & 1;
    const int r32 = lane & 31, hf = lane >> 5;
    const int lid = blockIdx.x;
    const int xcd = lid & 7, t = lid >> 3;
    const int nbk = t & ((1 << LOGNB) - 1);
    const int mbk = (xcd << 4) + (t >> LOGNB);   // 16 bands per XCD
    const long m0 = (long)mbk * 128;
    const long n0 = (long)nbk * 128;

    f32x16 acc[2][2];
    for (int mt = 0; mt < 2; mt++)
        for (int nt = 0; nt < 2; nt++)
            for (int r = 0; r < 16; r++) acc[mt][nt][r] = 0.f;

    for (long k0 = 0; k0 < K; k0 += 128) {
        __syncthreads();
        for (int i = 0; i < 4; i++) {
            const int c = tid + 256 * i;            // 0..1023: 128 rows x 8 chunks
            const int row = c >> 3, pos = c & 7;
            const int g = pos ^ (row & 7);          // source global chunk
            const u8* ga = A + (m0 + row) * K + k0 + g * 16;
            const u8* gb = Bt + (n0 + row) * K + k0 + g * 16;
            __builtin_amdgcn_global_load_lds((const __attribute__((address_space(1))) void*)ga,
                                             (__attribute__((address_space(3))) void*)(&lA[c * 16]), 16, 0, 0);
            __builtin_amdgcn_global_load_lds((const __attribute__((address_space(1))) void*)gb,
                                             (__attribute__((address_space(3))) void*)(&lB[c * 16]), 16, 0, 0);
        }
        __syncthreads();
        for (int km = 0; km < 2; km++) {
            const int cb = km * 4 + hf * 2;         // first 16B chunk of this lane's 32B
            i32x8 af[2], bfr[2];
            for (int mt = 0; mt < 2; mt++)
                af[mt] = frag32(lA, wm * 64 + mt * 32 + r32, cb);
            for (int nt = 0; nt < 2; nt++)
                bfr[nt] = frag32(lB, wn * 64 + nt * 32 + r32, cb);
            for (int mt = 0; mt < 2; mt++)
                for (int nt = 0; nt < 2; nt++)
                    acc[mt][nt] = __builtin_amdgcn_mfma_scale_f32_32x32x64_f8f6f4(
                        af[mt], bfr[nt], acc[mt][nt], 0, 0,
                        0, SCALE_ONE, 0, SCALE_ONE);
        }
    }

    // epilogue: C/D 32x32 layout: col=lane&31, row=(reg&3)+8*(reg>>2)+4*(lane>>5)
    for (int nt = 0; nt < 2; nt++) {
        const int col = (int)n0 + wn * 64 + nt * 32 + r32;
        const float bcol = bias[col];
        float s = 0.f, sq = 0.f;
        for (int mt = 0; mt < 2; mt++)
            for (int r = 0; r < 16; r++) {
                const long row = m0 + wm * 64 + mt * 32 + 4 * hf + (r & 3) + 8 * (r >> 2);
                float v = acc[mt][nt][r] * inv + bcol;
                v = fmaxf(v, 0.f);
                C[row * N + col] = f2fp8(v);
                s += v; sq += v * v;
            }
        s += __shfl_xor(s, 32);
        sq += __shfl_xor(sq, 32);
        if (hf == 0) { atomicAdd(&sums[col], s); atomicAdd(&ssq[col], sq); }
    }
}

// ---------------------------------------------------------------------------
// Kernel 4: fused middle stage (BN1 stats -> W2 scale-transpose + bias adjust).
//  blocks 0..511:  transpose W2 (1024x512) -> w2f (512x1024) with per-row
//                  a1[k] = g1*rsqrt(var+eps) recomputed inline from sums/ssq.
//  blocks 512..519: b2a[col] = b2[col] + sum_k c1[k]*W2[k,col], c1 from LDS.
// ---------------------------------------------------------------------------
__global__ __launch_bounds__(256) void k_mid(const float* __restrict__ sums1,
                                             const float* __restrict__ ssq1,
                                             const float* __restrict__ g1,
                                             const float* __restrict__ beta1,
                                             const float* __restrict__ W2,
                                             const float* __restrict__ b2,
                                             u8* __restrict__ w2f,
                                             float* __restrict__ b2a) {
    const int bid = blockIdx.x;
    if (bid < 512) {
        __shared__ float tile[32][33];
        __shared__ float sc[32];
        const int nb = (bid & 15) * 32;          // 16 col-blocks over N=512
        const int kb = (bid >> 4) * 32;          // 32 row-blocks over K=1024
        const int tx = threadIdx.x & 31, ty = threadIdx.x >> 5;
        if (threadIdx.x < 32) {
            const int k = kb + threadIdx.x;
            const float m = sums1[k] * INVB;
            const float var = ssq1[k] * INVB - m * m;
            sc[threadIdx.x] = g1[k] * rsqrtf(var + 1e-5f);
        }
        __syncthreads();
        for (int r = ty; r < 32; r += 8)
            tile[r][tx] = sc[r] * W2[(long)(kb + r) * 512 + nb + tx];
        __syncthreads();
        for (int r = ty; r < 32; r += 8)
            w2f[(long)(nb + r) * 1024 + kb + tx] = f2fp8(WSCALE * tile[tx][r]);
    } else {
        __shared__ float c1s[1024];
        __shared__ float part[4][64];
        for (int k = threadIdx.x; k < 1024; k += 256) {
            const float m = sums1[k] * INVB;
            const float var = ssq1[k] * INVB - m * m;
            const float a = g1[k] * rsqrtf(var + 1e-5f);
            c1s[k] = beta1[k] - a * m;
        }
        __syncthreads();
        const int lane = threadIdx.x & 63, w = threadIdx.x >> 6;
        const int col = (bid - 512) * 64 + lane;
        float s = 0.f;
        for (int k = w * 256; k < w * 256 + 256; k++)
            s += c1s[k] * W2[(long)k * 512 + col];
        part[w][lane] = s;
        __syncthreads();
        if (w == 0)
            b2a[col] = b2[col] + part[0][lane] + part[1][lane] + part[2][lane] + part[3][lane];
    }
}

// ---------------------------------------------------------------------------
// Kernel 5: stat2 + head-fold in one dispatch.
// ---------------------------------------------------------------------------
__global__ void k_stat2v(const float* __restrict__ sums, const float* __restrict__ ssq,
                         const float* __restrict__ g, const float* __restrict__ beta,
                         float* __restrict__ a, float* __restrict__ c, float invB,
                         const float* __restrict__ W3, const float* __restrict__ b3,
                         const float* __restrict__ Wc, const float* __restrict__ bc,
                         float* __restrict__ v, float* __restrict__ c0) {
    if (blockIdx.x < 2) {
        const int k = blockIdx.x * 256 + threadIdx.x;
        const float m = sums[k] * invB;
        const float var = ssq[k] * invB - m * m;
        const float s = g[k] * rsqrtf(var + 1e-5f);
        a[k] = s; c[k] = beta[k] - s * m;
    } else {
        for (int k = threadIdx.x; k < 512; k += 256) {
            float s = 0.f;
            for (int j = 0; j < 64; j++) s += W3[k * 64 + j] * Wc[j];
            v[k] = s;
        }
        if (threadIdx.x == 0) {
            float s = 0.f;
            for (int j = 0; j < 64; j++) s += b3[j] * Wc[j];
            *c0 = s + bc[0];
        }
    }
}

// ---------------------------------------------------------------------------
// Kernel 6: out[b] = sum_k (a2[k]*h2[b,k]+c2[k])*v[k] + spair[b] + c0
// ---------------------------------------------------------------------------
__global__ __launch_bounds__(256) void k_final(const u8* __restrict__ h2,
                                               const float* __restrict__ a2,
                                               const float* __restrict__ c2,
                                               const float* __restrict__ v,
                                               const float* __restrict__ c0,
                                               const float* __restrict__ spair,
                                               float* __restrict__ out) {
    const int wave = threadIdx.x >> 6, lane = threadIdx.x & 63;
    const long b = (long)blockIdx.x * 4 + wave;
    const int k0 = lane * 8;
    uint2 hv = *(const uint2*)&h2[b * 512 + k0];
    float f[8];
    f[0] = __builtin_amdgcn_cvt_f32_fp8(hv.x, 0);
    f[1] = __builtin_amdgcn_cvt_f32_fp8(hv.x, 1);
    f[2] = __builtin_amdgcn_cvt_f32_fp8(hv.x, 2);
    f[3] = __builtin_amdgcn_cvt_f32_fp8(hv.x, 3);
    f[4] = __builtin_amdgcn_cvt_f32_fp8(hv.y, 0);
    f[5] = __builtin_amdgcn_cvt_f32_fp8(hv.y, 1);
    f[6] = __builtin_amdgcn_cvt_f32_fp8(hv.y, 2);
    f[7] = __builtin_amdgcn_cvt_f32_fp8(hv.y, 3);
    float acc = 0.f;
    for (int j = 0; j < 8; j++) {
        const int k = k0 + j;
        acc += (a2[k] * f[j] + c2[k]) * v[k];
    }
    for (int off = 1; off < 64; off <<= 1) acc += __shfl_xor(acc, off);
    if (lane == 0) out[b] = acc + spair[b] + c0[0];
}

// ---------------------------------------------------------------------------
extern "C" void kernel_launch(void* const* d_in, const int* in_sizes, int n_in,
                              void* d_out, int out_size, void* d_ws, size_t ws_size,
                              hipStream_t stream) {
    const float* x     = (const float*)d_in[0];
    const float* W1    = (const float*)d_in[1];
    const float* b1    = (const float*)d_in[2];
    const float* g1    = (const float*)d_in[3];
    const float* beta1 = (const float*)d_in[4];
    const float* W2    = (const float*)d_in[5];
    const float* b2    = (const float*)d_in[6];
    const float* g2    = (const float*)d_in[7];
    const float* beta2 = (const float*)d_in[8];
    const float* W3    = (const float*)d_in[9];
    const float* b3    = (const float*)d_in[10];
    const float* Wc    = (const float*)d_in[11];
    const float* bc    = (const float*)d_in[12];
    float* out = (float*)d_out;

    char* ws = (char*)d_ws;
    size_t o = 0;
    u8* xb  = (u8*)(ws + o); o += BATCH * 2048;             // 33.6 MB fp8
    u8* w1f = (u8*)(ws + o); o += 2048L * 1024;             //  2.1 MB
    u8* w2f = (u8*)(ws + o); o += 1024L * 512;              //  0.5 MB
    u8* h1b = (u8*)(ws + o); o += BATCH * 1024;             // 16.8 MB (raw relu1, fp8)
    u8* h2b = (u8*)(ws + o); o += BATCH * 512;              //  8.4 MB (raw relu2, fp8)
    float* spair = (float*)(ws + o); o += BATCH * 4;
    float* stats = (float*)(ws + o); o += 3072 * 4;
    float* sums1 = stats, *ssq1 = stats + 1024, *sums2 = stats + 2048, *ssq2 = stats + 2560;
    float* a2 = (float*)(ws + o); o += 512 * 4;
    float* c2 = (float*)(ws + o); o += 512 * 4;
    float* vv = (float*)(ws + o); o += 512 * 4;
    float* c0 = (float*)(ws + o); o += 4;
    float* b2a = (float*)(ws + o); o += 512 * 4;

    k_gram<<<4096, 256, 0, stream>>>(x, Wc, xb, spair, stats);
    k_transpose_fp8<<<dim3(1024 / 32, 2048 / 32), 256, 0, stream>>>(W1, w1f, 2048, 1024);
    gemm_bn<3><<<1024, 256, 0, stream>>>(xb, w1f, b1, h1b, sums1, ssq1, 1024, 2048, INV_WSCALE);
    k_mid<<<520, 256, 0, stream>>>(sums1, ssq1, g1, beta1, W2, b2, w2f, b2a);
    gemm_bn<2><<<512, 256, 0, stream>>>(h1b, w2f, b2a, h2b, sums2, ssq2, 512, 1024, INV_WSCALE);
    k_stat2v<<<3, 256, 0, stream>>>(sums2, ssq2, g2, beta2, a2, c2, INVB,
                                    W3, b3, Wc, bc, vv, c0);
    k_final<<<4096, 256, 0, stream>>>(h2b, a2, c2, vv, c0, spair, out);
}